// Round 1
// baseline (3908.746 us; speedup 1.0000x reference)
//
#include <hip/hip_runtime.h>
#include <math.h>

namespace {
constexpr int kB = 2;
constexpr int kN = 1024;
constexpr int kM = 16384;
constexpr float kSqrt3 = 1.7320508075688772f;

// workspace layout in floats
constexpr size_t A_OFF = 0;                              // [B,N,N] A then L (lower)
constexpr size_t D_OFF = A_OFF + (size_t)kB * kN * kN;   // [B,8,128,128] inv of diag blocks
constexpr size_t G_OFF = D_OFF + (size_t)kB * 8 * 128 * 128;   // [B,28,128,128] L_ik * D_k
constexpr size_t Z_OFF = G_OFF + (size_t)kB * 28 * 128 * 128;  // [B,N] z = L^-1 (y-mean)
constexpr size_t K_OFF = Z_OFF + (size_t)kB * kN;        // [B,N,M] K_nm -> S -> w (in place)
constexpr size_t WS_FLOATS = K_OFF + (size_t)kB * kN * kM;
}  // namespace

__device__ __forceinline__ float pair_kernel(
    float x0, float x1, float a1, float b1, float c1,
    float y0, float y1, float a2, float b2, float c2, float scale) {
  float det1 = a1 * b1 - c1 * c1;
  float det2 = a2 * b2 - c2 * c2;
  float s00 = a1 + a2, s11 = b1 + b2, s01 = c1 + c2;
  float sdet = s00 * s11 - s01 * s01;
  float d0 = x0 - y0, d1 = x1 - y1;
  float Q = 0.5f * (s11 * d0 * d0 - 2.0f * s01 * d0 * d1 + s00 * d1 * d1) / sdet;
  float C = 2.0f * sqrtf(sqrtf(det1)) * sqrtf(sqrtf(det2)) * rsqrtf(fmaxf(sdet, 1e-5f));
  float t = kSqrt3 * sqrtf(fmaxf(Q, 1e-5f));
  return (1.0f + t) * __expf(-t) * C * scale;
}

// ---------------- A = K_nn + diag(var) ----------------
__global__ __launch_bounds__(256) void build_A(
    const float* __restrict__ xt, const float* __restrict__ pt,
    const float* __restrict__ var, const float* __restrict__ sp,
    float* __restrict__ A) {
  int idx = blockIdx.x * 256 + threadIdx.x;  // B*N*N
  int b = idx / (kN * kN);
  int r = (idx / kN) % kN;
  int c = idx % kN;
  float scale = __expf(sp[0]);
  const float* x1 = xt + ((size_t)b * kN + r) * 2;
  const float* p1 = pt + ((size_t)b * kN + r) * 3;
  const float* x2 = xt + ((size_t)b * kN + c) * 2;
  const float* p2 = pt + ((size_t)b * kN + c) * 3;
  float k = pair_kernel(x1[0], x1[1], p1[0], p1[1], p1[2],
                        x2[0], x2[1], p2[0], p2[1], p2[2], scale);
  if (r == c) k += var[b * kN + r];
  A[(size_t)idx] = k;
}

// ---------------- Cholesky panel factor (128x128) + explicit inverse ----------------
__global__ __launch_bounds__(128) void chol_panel(float* __restrict__ A,
                                                  float* __restrict__ Dg, int p) {
  __shared__ float Lt[128 * 129];
  __shared__ float Dt[128 * 129];
  __shared__ float Tt[3 * 32 * 33];
  int b = blockIdx.x;
  int t = threadIdx.x;
  float* Ab = A + (size_t)b * kN * kN;
  int r0 = p * 128;
  for (int r = 0; r < 128; ++r) Lt[r * 129 + t] = Ab[(size_t)(r0 + r) * kN + r0 + t];
  __syncthreads();
  // in-LDS right-looking Cholesky (lower)
  for (int k = 0; k < 128; ++k) {
    float akk = Lt[k * 129 + k];
    float d = sqrtf(akk);
    float inv = 1.0f / d;
    __syncthreads();
    if (t == k) Lt[k * 129 + k] = d;
    else if (t > k) Lt[t * 129 + k] *= inv;
    __syncthreads();
    if (t > k) {
      float lik = Lt[t * 129 + k];
      for (int j = k + 1; j <= t; ++j)
        Lt[t * 129 + j] = fmaf(-lik, Lt[j * 129 + k], Lt[t * 129 + j]);
    }
    __syncthreads();
  }
  // ---- invert the 128x128 lower triangle into Dt, sub-blocked by 32 ----
  {
    int q = t >> 5, c = t & 31, base = q * 32;
    for (int r = 0; r < 32; ++r) {
      float x;
      if (r < c) x = 0.0f;
      else if (r == c) x = 1.0f / Lt[(base + r) * 129 + base + r];
      else {
        float s = 0.0f;
        for (int j = c; j < r; ++j)
          s += Lt[(base + r) * 129 + base + j] * Dt[(base + j) * 129 + base + c];
        x = -s / Lt[(base + r) * 129 + base + r];
      }
      Dt[(base + r) * 129 + base + c] = x;
    }
  }
  for (int s = 1; s <= 3; ++s) {
    __syncthreads();
    for (int blk = 0; blk < 4 - s; ++blk) {
      int J = blk, I = J + s;
      for (int ii = 0; ii < 8; ++ii) {
        int e = t + 128 * ii;
        int r = e >> 5, cl = e & 31;
        float sum = 0.0f;
        for (int K = J; K < I; ++K)
          for (int j = 0; j < 32; ++j)
            sum += Lt[(I * 32 + r) * 129 + K * 32 + j] * Dt[(K * 32 + j) * 129 + J * 32 + cl];
        Tt[blk * (32 * 33) + r * 33 + cl] = sum;
      }
    }
    __syncthreads();
    for (int blk = 0; blk < 4 - s; ++blk) {
      int J = blk, I = J + s;
      for (int ii = 0; ii < 8; ++ii) {
        int e = t + 128 * ii;
        int r = e >> 5, cl = e & 31;
        float sum = 0.0f;
        for (int j = 0; j < 32; ++j)
          sum += Dt[(I * 32 + r) * 129 + I * 32 + j] * Tt[blk * (32 * 33) + j * 33 + cl];
        Dt[(I * 32 + r) * 129 + J * 32 + cl] = -sum;
      }
    }
  }
  __syncthreads();
  // write back L panel and D block (zero upper)
  for (int r = 0; r < 128; ++r) Ab[(size_t)(r0 + r) * kN + r0 + t] = Lt[r * 129 + t];
  float* Db = Dg + (size_t)(b * 8 + p) * 16384;
  for (int r = 0; r < 128; ++r) Db[r * 128 + t] = (r >= t) ? Dt[r * 129 + t] : 0.0f;
}

// ---------------- L21 = A21 * D_p^T (in place over A21) ----------------
__global__ __launch_bounds__(256) void chol_trsm(float* __restrict__ A,
                                                 const float* __restrict__ Dg, int p) {
  __shared__ float At[128 * 129];
  __shared__ float Dt[128 * 129];
  int b = blockIdx.y, rb = blockIdx.x;
  int rs = (p + 1 + rb) * 128;
  float* Ab = A + (size_t)b * kN * kN;
  const float* Db = Dg + (size_t)(b * 8 + p) * 16384;
  int t = threadIdx.x;
  for (int q = 0; q < 64; ++q) {
    int li = t + 256 * q;
    int r = li >> 7, cc = li & 127;
    At[r * 129 + cc] = Ab[(size_t)(rs + r) * kN + p * 128 + cc];
    Dt[r * 129 + cc] = Db[r * 128 + cc];
  }
  __syncthreads();
  int tx = t & 15, ty = t >> 4;
  float acc[8][8] = {};
  for (int j = 0; j < 128; ++j) {
    float a[8], d[8];
#pragma unroll
    for (int q = 0; q < 8; ++q) a[q] = At[(ty * 8 + q) * 129 + j];
#pragma unroll
    for (int q = 0; q < 8; ++q) d[q] = Dt[(tx * 8 + q) * 129 + j];
#pragma unroll
    for (int qr = 0; qr < 8; ++qr)
#pragma unroll
      for (int qc = 0; qc < 8; ++qc) acc[qr][qc] = fmaf(a[qr], d[qc], acc[qr][qc]);
  }
#pragma unroll
  for (int qr = 0; qr < 8; ++qr)
#pragma unroll
    for (int qc = 0; qc < 8; ++qc)
      Ab[(size_t)(rs + ty * 8 + qr) * kN + p * 128 + tx * 8 + qc] = acc[qr][qc];
}

// ---------------- A22 -= L21 * L21^T ----------------
__global__ __launch_bounds__(256) void chol_syrk(float* __restrict__ A, int p) {
  __shared__ float L1t[128 * 129];
  __shared__ float L2t[128 * 129];
  int b = blockIdx.y;
  int pid = blockIdx.x;
  int bi = 0;
  while ((bi + 1) * (bi + 2) / 2 <= pid) ++bi;
  int bj = pid - bi * (bi + 1) / 2;
  int rs1 = (p + 1 + bi) * 128, rs2 = (p + 1 + bj) * 128;
  float* Ab = A + (size_t)b * kN * kN;
  int t = threadIdx.x;
  for (int q = 0; q < 64; ++q) {
    int li = t + 256 * q;
    int r = li >> 7, cc = li & 127;
    L1t[r * 129 + cc] = Ab[(size_t)(rs1 + r) * kN + p * 128 + cc];
    L2t[r * 129 + cc] = Ab[(size_t)(rs2 + r) * kN + p * 128 + cc];
  }
  __syncthreads();
  int tx = t & 15, ty = t >> 4;
  float acc[8][8] = {};
  for (int j = 0; j < 128; ++j) {
    float a[8], d[8];
#pragma unroll
    for (int q = 0; q < 8; ++q) a[q] = L1t[(ty * 8 + q) * 129 + j];
#pragma unroll
    for (int q = 0; q < 8; ++q) d[q] = L2t[(tx * 8 + q) * 129 + j];
#pragma unroll
    for (int qr = 0; qr < 8; ++qr)
#pragma unroll
      for (int qc = 0; qc < 8; ++qc) acc[qr][qc] = fmaf(a[qr], d[qc], acc[qr][qc]);
  }
#pragma unroll
  for (int qr = 0; qr < 8; ++qr)
#pragma unroll
    for (int qc = 0; qc < 8; ++qc) {
      size_t o = (size_t)(rs1 + ty * 8 + qr) * kN + rs2 + tx * 8 + qc;
      Ab[o] -= acc[qr][qc];
    }
}

// ---------------- G_ik = L_ik * D_k ----------------
__global__ __launch_bounds__(256) void build_G(const float* __restrict__ A,
                                               const float* __restrict__ Dg,
                                               float* __restrict__ G) {
  __shared__ float Lt[128 * 129];
  __shared__ float Dt[128 * 129];
  int b = blockIdx.y;
  int pid = blockIdx.x;
  int i = 1;
  while ((i * (i + 1)) / 2 <= pid) ++i;
  int k = pid - (i * (i - 1)) / 2;
  const float* Ab = A + (size_t)b * kN * kN;
  const float* Db = Dg + (size_t)(b * 8 + k) * 16384;
  int t = threadIdx.x;
  for (int q = 0; q < 64; ++q) {
    int li = t + 256 * q;
    int r = li >> 7, cc = li & 127;
    Lt[r * 129 + cc] = Ab[(size_t)(i * 128 + r) * kN + k * 128 + cc];
    Dt[r * 129 + cc] = Db[r * 128 + cc];
  }
  __syncthreads();
  int tx = t & 15, ty = t >> 4;
  float acc[8][8] = {};
  for (int j = 0; j < 128; ++j) {
    float a[8], d[8];
#pragma unroll
    for (int q = 0; q < 8; ++q) a[q] = Lt[(ty * 8 + q) * 129 + j];
#pragma unroll
    for (int q = 0; q < 8; ++q) d[q] = Dt[j * 129 + tx * 8 + q];
#pragma unroll
    for (int qr = 0; qr < 8; ++qr)
#pragma unroll
      for (int qc = 0; qc < 8; ++qc) acc[qr][qc] = fmaf(a[qr], d[qc], acc[qr][qc]);
  }
  float* Gb = G + (size_t)(b * 28 + pid) * 16384;
#pragma unroll
  for (int qr = 0; qr < 8; ++qr)
#pragma unroll
    for (int qc = 0; qc < 8; ++qc)
      Gb[(ty * 8 + qr) * 128 + tx * 8 + qc] = acc[qr][qc];
}

// ---------------- z = L^-1 (y - mean), nlml ----------------
__global__ __launch_bounds__(128) void solve_small(
    const float* __restrict__ A, const float* __restrict__ Dg,
    const float* __restrict__ y, const float* __restrict__ meanp,
    float* __restrict__ zbuf, float* __restrict__ out) {
  __shared__ float zs[1024];
  __shared__ float ts[128];
  __shared__ float red[128];
  int b = blockIdx.x, t = threadIdx.x;
  const float* Ab = A + (size_t)b * kN * kN;
  float mv = meanp[b];
  for (int q = t; q < 1024; q += 128) zs[q] = y[b * kN + q] - mv;
  __syncthreads();
  for (int i = 0; i < 8; ++i) {
    float acc = zs[i * 128 + t];
    const float* Lrow = Ab + (size_t)(i * 128 + t) * kN;
    for (int kk = 0; kk < i * 128; ++kk) acc -= Lrow[kk] * zs[kk];
    ts[t] = acc;
    __syncthreads();
    const float* Db = Dg + (size_t)(b * 8 + i) * 16384 + t * 128;
    float zv = 0.0f;
    for (int c = 0; c <= t; ++c) zv += Db[c] * ts[c];
    zs[i * 128 + t] = zv;
    __syncthreads();
  }
  float df = 0.0f, ld = 0.0f;
  for (int q = t; q < 1024; q += 128) {
    df += zs[q] * zs[q];
    ld += logf(Ab[(size_t)q * kN + q]);
  }
  red[t] = df;
  __syncthreads();
  for (int s = 64; s > 0; s >>= 1) {
    if (t < s) red[t] += red[t + s];
    __syncthreads();
  }
  float dfs = red[0];
  __syncthreads();
  red[t] = ld;
  __syncthreads();
  for (int s = 64; s > 0; s >>= 1) {
    if (t < s) red[t] += red[t + s];
    __syncthreads();
  }
  if (t == 0)
    out[2 * kB * kM + b] = 0.5f * dfs + red[0] + 0.5f * 1024.0f * logf(6.283185307179586f);
  for (int q = t; q < 1024; q += 128) zbuf[b * kN + q] = zs[q];
}

// ---------------- K_nm ----------------
__global__ __launch_bounds__(256) void build_Knm(
    const float* __restrict__ xt, const float* __restrict__ pt,
    const float* __restrict__ xs, const float* __restrict__ ps,
    const float* __restrict__ sp, float* __restrict__ Kw) {
  size_t idx = (size_t)blockIdx.x * 256 + threadIdx.x;  // B*N*M
  int b = (int)(idx / ((size_t)kN * kM));
  int n = (int)((idx / kM) % kN);
  int m = (int)(idx % kM);
  float scale = __expf(sp[0]);
  const float* x1 = xt + ((size_t)b * kN + n) * 2;
  const float* p1 = pt + ((size_t)b * kN + n) * 3;
  const float* x2 = xs + ((size_t)b * kM + m) * 2;
  const float* p2 = ps + ((size_t)b * kM + m) * 3;
  Kw[idx] = pair_kernel(x1[0], x1[1], p1[0], p1[1], p1[2],
                        x2[0], x2[1], p2[0], p2[1], p2[2], scale);
}

// ---------------- S_i = K_i - sum_{k<i} G_ik S_k (in place) ----------------
__global__ __launch_bounds__(256) void trsm_step(const float* __restrict__ G,
                                                 float* __restrict__ Kw, int ib) {
  __shared__ float At[32 * 132];
  __shared__ float Bt[32 * 132];
  int b = blockIdx.y;
  int m0 = blockIdx.x * 128;
  int t = threadIdx.x;
  int tx = t & 15, ty = t >> 4;
  float acc[8][8] = {};
  for (int kb = 0; kb < ib; ++kb) {
    const float* Gblk = G + (size_t)(b * 28 + (ib * (ib - 1)) / 2 + kb) * 16384;
    for (int kc = 0; kc < 128; kc += 32) {
#pragma unroll
      for (int q = 0; q < 4; ++q) {
        int li = t + 256 * q;
        int r = li >> 3, k4 = li & 7;
        float4 v = *(const float4*)(Gblk + r * 128 + kc + k4 * 4);
        At[(k4 * 4 + 0) * 132 + r] = v.x;
        At[(k4 * 4 + 1) * 132 + r] = v.y;
        At[(k4 * 4 + 2) * 132 + r] = v.z;
        At[(k4 * 4 + 3) * 132 + r] = v.w;
      }
#pragma unroll
      for (int q = 0; q < 4; ++q) {
        int li = t + 256 * q;
        int kk = li >> 5, m4 = li & 31;
        float4 v = *(const float4*)(Kw + ((size_t)b * kN + kb * 128 + kc + kk) * kM + m0 + m4 * 4);
        *(float4*)(Bt + kk * 132 + m4 * 4) = v;
      }
      __syncthreads();
#pragma unroll
      for (int kk = 0; kk < 32; ++kk) {
        float a[8], w[8];
        *(float4*)a = *(const float4*)(At + kk * 132 + ty * 8);
        *(float4*)(a + 4) = *(const float4*)(At + kk * 132 + ty * 8 + 4);
        *(float4*)w = *(const float4*)(Bt + kk * 132 + tx * 8);
        *(float4*)(w + 4) = *(const float4*)(Bt + kk * 132 + tx * 8 + 4);
#pragma unroll
        for (int qr = 0; qr < 8; ++qr)
#pragma unroll
          for (int qc = 0; qc < 8; ++qc) acc[qr][qc] = fmaf(a[qr], w[qc], acc[qr][qc]);
      }
      __syncthreads();
    }
  }
#pragma unroll
  for (int qr = 0; qr < 8; ++qr) {
    float* rowp = Kw + ((size_t)b * kN + ib * 128 + ty * 8 + qr) * kM + m0 + tx * 8;
    float4 k0 = *(const float4*)rowp;
    float4 k1 = *(const float4*)(rowp + 4);
    k0.x -= acc[qr][0]; k0.y -= acc[qr][1]; k0.z -= acc[qr][2]; k0.w -= acc[qr][3];
    k1.x -= acc[qr][4]; k1.y -= acc[qr][5]; k1.z -= acc[qr][6]; k1.w -= acc[qr][7];
    *(float4*)rowp = k0;
    *(float4*)(rowp + 4) = k1;
  }
}

// ---------------- w_i = D_i S_i (in place, all blocks) ----------------
__global__ __launch_bounds__(256) void dmult(const float* __restrict__ Dg,
                                             float* __restrict__ Kw) {
  __shared__ float At[32 * 132];
  __shared__ float Bt[32 * 132];
  int b = blockIdx.y >> 3;
  int ib = blockIdx.y & 7;
  int m0 = blockIdx.x * 128;
  const float* Db = Dg + (size_t)(b * 8 + ib) * 16384;
  int t = threadIdx.x;
  int tx = t & 15, ty = t >> 4;
  float acc[8][8] = {};
  for (int kc = 0; kc < 128; kc += 32) {
#pragma unroll
    for (int q = 0; q < 4; ++q) {
      int li = t + 256 * q;
      int r = li >> 3, c4 = li & 7;
      float4 v = *(const float4*)(Db + r * 128 + kc + c4 * 4);
      At[(c4 * 4 + 0) * 132 + r] = v.x;
      At[(c4 * 4 + 1) * 132 + r] = v.y;
      At[(c4 * 4 + 2) * 132 + r] = v.z;
      At[(c4 * 4 + 3) * 132 + r] = v.w;
    }
#pragma unroll
    for (int q = 0; q < 4; ++q) {
      int li = t + 256 * q;
      int kk = li >> 5, m4 = li & 31;
      float4 v = *(const float4*)(Kw + ((size_t)b * kN + ib * 128 + kc + kk) * kM + m0 + m4 * 4);
      *(float4*)(Bt + kk * 132 + m4 * 4) = v;
    }
    __syncthreads();
#pragma unroll
    for (int kk = 0; kk < 32; ++kk) {
      float a[8], w[8];
      *(float4*)a = *(const float4*)(At + kk * 132 + ty * 8);
      *(float4*)(a + 4) = *(const float4*)(At + kk * 132 + ty * 8 + 4);
      *(float4*)w = *(const float4*)(Bt + kk * 132 + tx * 8);
      *(float4*)(w + 4) = *(const float4*)(Bt + kk * 132 + tx * 8 + 4);
#pragma unroll
      for (int qr = 0; qr < 8; ++qr)
#pragma unroll
        for (int qc = 0; qc < 8; ++qc) acc[qr][qc] = fmaf(a[qr], w[qc], acc[qr][qc]);
    }
    __syncthreads();
  }
#pragma unroll
  for (int qr = 0; qr < 8; ++qr) {
    float* dst = Kw + ((size_t)b * kN + ib * 128 + ty * 8 + qr) * kM + m0 + tx * 8;
    float4 v0 = {acc[qr][0], acc[qr][1], acc[qr][2], acc[qr][3]};
    float4 v1 = {acc[qr][4], acc[qr][5], acc[qr][6], acc[qr][7]};
    *(float4*)dst = v0;
    *(float4*)(dst + 4) = v1;
  }
}

// ---------------- pred_mean / pred_var ----------------
__global__ __launch_bounds__(256) void finalize(
    const float* __restrict__ Kw, const float* __restrict__ zbuf,
    const float* __restrict__ ps, const float* __restrict__ sp,
    const float* __restrict__ meanp, float* __restrict__ out) {
  int idx = blockIdx.x * 256 + threadIdx.x;  // B*M
  int b = idx / kM;
  int m = idx % kM;
  __shared__ float zsh[1024];
  for (int q = threadIdx.x; q < 1024; q += 256) zsh[q] = zbuf[b * kN + q];
  __syncthreads();
  float pm = 0.0f, s2 = 0.0f;
  const float* col = Kw + (size_t)b * kN * kM + m;
  for (int n = 0; n < kN; ++n) {
    float wv = col[(size_t)n * kM];
    pm = fmaf(wv, zsh[n], pm);
    s2 = fmaf(wv, wv, s2);
  }
  float a = ps[(size_t)(b * kM + m) * 3 + 0];
  float bb = ps[(size_t)(b * kM + m) * 3 + 1];
  float c = ps[(size_t)(b * kM + m) * 3 + 2];
  float det = a * bb - c * c;
  float C = 2.0f * sqrtf(det) * rsqrtf(fmaxf(4.0f * det, 1e-5f));
  float t0 = kSqrt3 * sqrtf(1e-5f);
  float mat = (1.0f + t0) * __expf(-t0);
  float scale = __expf(sp[0]);
  float kd = C * mat * scale;
  out[b * kM + m] = meanp[b] + pm;
  out[kB * kM + b * kM + m] = kd - s2;
}

extern "C" void kernel_launch(void* const* d_in, const int* in_sizes, int n_in,
                              void* d_out, int out_size, void* d_ws, size_t ws_size,
                              hipStream_t stream) {
  const float* xt = (const float*)d_in[0];   // coords_train [B,N,2]
  const float* pt = (const float*)d_in[1];   // kernel_params_train [B,N,3]
  const float* xs = (const float*)d_in[2];   // coords_test [B,M,2]
  const float* ps = (const float*)d_in[3];   // kernel_params_test [B,M,3]
  const float* y = (const float*)d_in[4];    // y_train [B,N,1]
  const float* var = (const float*)d_in[5];  // var [B,N]
  const float* meanp = (const float*)d_in[6];// mean [B,1,1]
  const float* sp = (const float*)d_in[7];   // scale_param [1]
  float* out = (float*)d_out;
  float* ws = (float*)d_ws;
  if (ws_size < WS_FLOATS * sizeof(float)) return;  // workspace too small -> fail loudly

  float* A = ws + A_OFF;
  float* Dg = ws + D_OFF;
  float* G = ws + G_OFF;
  float* zbuf = ws + Z_OFF;
  float* Kw = ws + K_OFF;

  build_A<<<(kB * kN * kN) / 256, 256, 0, stream>>>(xt, pt, var, sp, A);
  for (int p = 0; p < 8; ++p) {
    chol_panel<<<kB, 128, 0, stream>>>(A, Dg, p);
    if (p < 7) {
      int nt = 7 - p;
      chol_trsm<<<dim3(nt, kB), 256, 0, stream>>>(A, Dg, p);
      chol_syrk<<<dim3(nt * (nt + 1) / 2, kB), 256, 0, stream>>>(A, p);
    }
  }
  build_G<<<dim3(28, kB), 256, 0, stream>>>(A, Dg, G);
  solve_small<<<kB, 128, 0, stream>>>(A, Dg, y, meanp, zbuf, out);
  build_Knm<<<(int)(((size_t)kB * kN * kM) / 256), 256, 0, stream>>>(xt, pt, xs, ps, sp, Kw);
  for (int i = 1; i < 8; ++i)
    trsm_step<<<dim3(kM / 128, kB), 256, 0, stream>>>(G, Kw, i);
  dmult<<<dim3(kM / 128, kB * 8), 256, 0, stream>>>(Dg, Kw);
  finalize<<<(kB * kM) / 256, 256, 0, stream>>>(Kw, zbuf, ps, sp, meanp, out);
}

// Round 2
// 2176.365 us; speedup vs baseline: 1.7960x; 1.7960x over previous
//
#include <hip/hip_runtime.h>
#include <math.h>

namespace {
constexpr int kB = 2;
constexpr int kN = 1024;
constexpr int kM = 16384;
constexpr float kSqrt3 = 1.7320508075688772f;

// workspace layout in floats
constexpr size_t A_OFF = 0;                              // [B,N,N] A then L (lower)
constexpr size_t D_OFF = A_OFF + (size_t)kB * kN * kN;   // [B,8,128,128] inv of diag blocks
constexpr size_t G_OFF = D_OFF + (size_t)kB * 8 * 128 * 128;   // [B,28,128,128] L_ik * D_k
constexpr size_t Z_OFF = G_OFF + (size_t)kB * 28 * 128 * 128;  // [B,N] z = L^-1 (y-mean)
constexpr size_t K_OFF = Z_OFF + (size_t)kB * kN;        // [B,N,M] K_nm -> S -> w (in place)
constexpr size_t WS_FLOATS = K_OFF + (size_t)kB * kN * kM;
}  // namespace

__device__ __forceinline__ float pair_kernel(
    float x0, float x1, float a1, float b1, float c1,
    float y0, float y1, float a2, float b2, float c2, float scale) {
  float det1 = a1 * b1 - c1 * c1;
  float det2 = a2 * b2 - c2 * c2;
  float s00 = a1 + a2, s11 = b1 + b2, s01 = c1 + c2;
  float sdet = s00 * s11 - s01 * s01;
  float d0 = x0 - y0, d1 = x1 - y1;
  float Q = 0.5f * (s11 * d0 * d0 - 2.0f * s01 * d0 * d1 + s00 * d1 * d1) / sdet;
  float C = 2.0f * sqrtf(sqrtf(det1)) * sqrtf(sqrtf(det2)) * rsqrtf(fmaxf(sdet, 1e-5f));
  float t = kSqrt3 * sqrtf(fmaxf(Q, 1e-5f));
  return (1.0f + t) * __expf(-t) * C * scale;
}

// ---------------- A = K_nn + diag(var) ----------------
__global__ __launch_bounds__(256) void build_A(
    const float* __restrict__ xt, const float* __restrict__ pt,
    const float* __restrict__ var, const float* __restrict__ sp,
    float* __restrict__ A) {
  int idx = blockIdx.x * 256 + threadIdx.x;  // B*N*N
  int b = idx / (kN * kN);
  int r = (idx / kN) % kN;
  int c = idx % kN;
  float scale = __expf(sp[0]);
  const float* x1 = xt + ((size_t)b * kN + r) * 2;
  const float* p1 = pt + ((size_t)b * kN + r) * 3;
  const float* x2 = xt + ((size_t)b * kN + c) * 2;
  const float* p2 = pt + ((size_t)b * kN + c) * 3;
  float k = pair_kernel(x1[0], x1[1], p1[0], p1[1], p1[2],
                        x2[0], x2[1], p2[0], p2[1], p2[2], scale);
  if (r == c) k += var[b * kN + r];
  A[(size_t)idx] = k;
}

// Lt swizzled indexers: panel [128][128] floats, f4-column XOR'd with (row>>2)&7.
// Stride-4-row b128 reads are bank-conflict-free-ish under this swizzle.
__device__ __forceinline__ int lt_idx4(int row, int f4) {  // word index of 16B group
  return row * 128 + ((f4 ^ ((row >> 2) & 7)) << 2);
}
__device__ __forceinline__ int lt_idx(int row, int col) {  // scalar word index
  return row * 128 + ((((col >> 2) ^ ((row >> 2) & 7)) << 2) | (col & 3));
}

// ---------------- Cholesky panel factor (128x128) + explicit inverse ----------------
// 1024 threads; each thread owns a 4x4 register tile (ty,tx); rank-4 rounds.
__global__ __launch_bounds__(1024) void chol_panel(float* __restrict__ A,
                                                   float* __restrict__ Dg, int p) {
  __shared__ float Lt[128 * 128];      // swizzled L panel
  __shared__ float Dt[128 * 132];      // inverse (linear, stride 132)
  __shared__ float Tt[3 * 32 * 33];
  int b = blockIdx.x;
  int t = threadIdx.x;
  float* Ab = A + (size_t)b * kN * kN;
  int r0 = p * 128;
  int tx = t & 31, ty = t >> 5;
  int i0 = ty * 4, j0 = tx * 4;
  bool lower = (ty >= tx);
  float acc[4][4];
  if (lower) {
#pragma unroll
    for (int q = 0; q < 4; ++q) {
      float4 v = *(const float4*)&Ab[(size_t)(r0 + i0 + q) * kN + r0 + j0];
      acc[q][0] = v.x; acc[q][1] = v.y; acc[q][2] = v.z; acc[q][3] = v.w;
    }
  }
  for (int kb = 0; kb < 32; ++kb) {
    int K0 = kb * 4;
    if (ty == kb && tx == kb) {
      // local 4x4 Cholesky on register tile
#pragma unroll
      for (int c = 0; c < 4; ++c) {
        float d = sqrtf(acc[c][c]);
        float inv = 1.0f / d;
        acc[c][c] = d;
#pragma unroll
        for (int i = c + 1; i < 4; ++i) acc[i][c] *= inv;
#pragma unroll
        for (int j = c + 1; j < 4; ++j)
#pragma unroll
          for (int i = j; i < 4; ++i) acc[i][j] -= acc[i][c] * acc[j][c];
      }
#pragma unroll
      for (int q = 0; q < 4; ++q) {
        float4 v;
        v.x = acc[q][0];
        v.y = (q >= 1) ? acc[q][1] : 0.0f;
        v.z = (q >= 2) ? acc[q][2] : 0.0f;
        v.w = (q >= 3) ? acc[q][3] : 0.0f;
        *(float4*)&Lt[lt_idx4(K0 + q, kb)] = v;
      }
    }
    __syncthreads();
    if (tx == kb && ty > kb) {
      // local triangular solve: tile <- tile * L4^{-T}
      float L4[4][4];
#pragma unroll
      for (int c = 0; c < 4; ++c)
#pragma unroll
        for (int j = 0; j <= c; ++j) L4[c][j] = Lt[lt_idx(K0 + c, K0 + j)];
#pragma unroll
      for (int c = 0; c < 4; ++c) {
#pragma unroll
        for (int j = 0; j < c; ++j) {
          float m = L4[c][j];
#pragma unroll
          for (int q = 0; q < 4; ++q) acc[q][c] -= m * acc[q][j];
        }
        float inv = 1.0f / L4[c][c];
#pragma unroll
        for (int q = 0; q < 4; ++q) acc[q][c] *= inv;
      }
#pragma unroll
      for (int q = 0; q < 4; ++q) {
        float4 v = {acc[q][0], acc[q][1], acc[q][2], acc[q][3]};
        *(float4*)&Lt[lt_idx4(i0 + q, kb)] = v;
      }
    }
    __syncthreads();
    if (tx > kb && lower) {
      float4 Ri[4], Rj[4];
#pragma unroll
      for (int q = 0; q < 4; ++q) Ri[q] = *(const float4*)&Lt[lt_idx4(i0 + q, kb)];
#pragma unroll
      for (int q = 0; q < 4; ++q) Rj[q] = *(const float4*)&Lt[lt_idx4(j0 + q, kb)];
#pragma unroll
      for (int qr = 0; qr < 4; ++qr)
#pragma unroll
        for (int qc = 0; qc < 4; ++qc)
          acc[qr][qc] -= Ri[qr].x * Rj[qc].x + Ri[qr].y * Rj[qc].y +
                         Ri[qr].z * Rj[qc].z + Ri[qr].w * Rj[qc].w;
    }
  }
  // ---- triangular inverse of the panel into Dt ----
  // base: four 32x32 diagonal blocks, one thread per column
  if (t < 128) {
    int q = t >> 5, c = t & 31, base = q * 32;
    for (int r = 0; r < 32; ++r) {
      float x;
      if (r < c) x = 0.0f;
      else if (r == c) x = 1.0f / Lt[lt_idx(base + r, base + r)];
      else {
        float s = 0.0f;
        for (int j = c; j < r; ++j)
          s += Lt[lt_idx(base + r, base + j)] * Dt[(base + j) * 132 + base + c];
        x = -s / Lt[lt_idx(base + r, base + r)];
      }
      Dt[(base + r) * 132 + base + c] = x;
    }
  }
  __syncthreads();
  {
    int r = t >> 5, cl = t & 31;
    for (int s = 1; s <= 3; ++s) {
      for (int blk = 0; blk < 4 - s; ++blk) {
        int J = blk, I = J + s;
        float sum = 0.0f;
        for (int K = J; K < I; ++K)
          for (int j = 0; j < 32; ++j)
            sum += Lt[lt_idx(I * 32 + r, K * 32 + j)] * Dt[(K * 32 + j) * 132 + J * 32 + cl];
        Tt[blk * (32 * 33) + r * 33 + cl] = sum;
      }
      __syncthreads();
      for (int blk = 0; blk < 4 - s; ++blk) {
        int J = blk, I = J + s;
        float sum = 0.0f;
        for (int j = 0; j < 32; ++j)
          sum += Dt[(I * 32 + r) * 132 + I * 32 + j] * Tt[blk * (32 * 33) + j * 33 + cl];
        Dt[(I * 32 + r) * 132 + J * 32 + cl] = -sum;
      }
      __syncthreads();
    }
  }
  // ---- writebacks: L panel (zero upper) and D block (zero upper) ----
#pragma unroll
  for (int q = 0; q < 4; ++q) {
    int j = t + 1024 * q;
    int r = j >> 5, ch = j & 31;
    float4 v = *(const float4*)&Lt[lt_idx4(r, ch)];
    int c0 = ch * 4;
    v.x = (c0 + 0 <= r) ? v.x : 0.0f;
    v.y = (c0 + 1 <= r) ? v.y : 0.0f;
    v.z = (c0 + 2 <= r) ? v.z : 0.0f;
    v.w = (c0 + 3 <= r) ? v.w : 0.0f;
    *(float4*)&Ab[(size_t)(r0 + r) * kN + r0 + c0] = v;
  }
  float* Db = Dg + (size_t)(b * 8 + p) * 16384;
#pragma unroll
  for (int q = 0; q < 4; ++q) {
    int j = t + 1024 * q;
    int r = j >> 5, ch = j & 31;
    float4 v = *(const float4*)&Dt[r * 132 + ch * 4];
    int c0 = ch * 4;
    v.x = (c0 + 0 <= r) ? v.x : 0.0f;
    v.y = (c0 + 1 <= r) ? v.y : 0.0f;
    v.z = (c0 + 2 <= r) ? v.z : 0.0f;
    v.w = (c0 + 3 <= r) ? v.w : 0.0f;
    *(float4*)&Db[r * 128 + c0] = v;
  }
}

// ---------------- L21 = A21 * D_p^T (in place over A21) ----------------
__global__ __launch_bounds__(256) void chol_trsm(float* __restrict__ A,
                                                 const float* __restrict__ Dg, int p) {
  __shared__ float At[128 * 129];
  __shared__ float Dt[128 * 129];
  int b = blockIdx.y, rb = blockIdx.x;
  int rs = (p + 1 + rb) * 128;
  float* Ab = A + (size_t)b * kN * kN;
  const float* Db = Dg + (size_t)(b * 8 + p) * 16384;
  int t = threadIdx.x;
  for (int q = 0; q < 64; ++q) {
    int li = t + 256 * q;
    int r = li >> 7, cc = li & 127;
    At[r * 129 + cc] = Ab[(size_t)(rs + r) * kN + p * 128 + cc];
    Dt[r * 129 + cc] = Db[r * 128 + cc];
  }
  __syncthreads();
  int tx = t & 15, ty = t >> 4;
  float acc[8][8] = {};
  for (int j = 0; j < 128; ++j) {
    float a[8], d[8];
#pragma unroll
    for (int q = 0; q < 8; ++q) a[q] = At[(ty * 8 + q) * 129 + j];
#pragma unroll
    for (int q = 0; q < 8; ++q) d[q] = Dt[(tx * 8 + q) * 129 + j];
#pragma unroll
    for (int qr = 0; qr < 8; ++qr)
#pragma unroll
      for (int qc = 0; qc < 8; ++qc) acc[qr][qc] = fmaf(a[qr], d[qc], acc[qr][qc]);
  }
#pragma unroll
  for (int qr = 0; qr < 8; ++qr)
#pragma unroll
    for (int qc = 0; qc < 8; ++qc)
      Ab[(size_t)(rs + ty * 8 + qr) * kN + p * 128 + tx * 8 + qc] = acc[qr][qc];
}

// ---------------- A22 -= L21 * L21^T ----------------
__global__ __launch_bounds__(256) void chol_syrk(float* __restrict__ A, int p) {
  __shared__ float L1t[128 * 129];
  __shared__ float L2t[128 * 129];
  int b = blockIdx.y;
  int pid = blockIdx.x;
  int bi = 0;
  while ((bi + 1) * (bi + 2) / 2 <= pid) ++bi;
  int bj = pid - bi * (bi + 1) / 2;
  int rs1 = (p + 1 + bi) * 128, rs2 = (p + 1 + bj) * 128;
  float* Ab = A + (size_t)b * kN * kN;
  int t = threadIdx.x;
  for (int q = 0; q < 64; ++q) {
    int li = t + 256 * q;
    int r = li >> 7, cc = li & 127;
    L1t[r * 129 + cc] = Ab[(size_t)(rs1 + r) * kN + p * 128 + cc];
    L2t[r * 129 + cc] = Ab[(size_t)(rs2 + r) * kN + p * 128 + cc];
  }
  __syncthreads();
  int tx = t & 15, ty = t >> 4;
  float acc[8][8] = {};
  for (int j = 0; j < 128; ++j) {
    float a[8], d[8];
#pragma unroll
    for (int q = 0; q < 8; ++q) a[q] = L1t[(ty * 8 + q) * 129 + j];
#pragma unroll
    for (int q = 0; q < 8; ++q) d[q] = L2t[(tx * 8 + q) * 129 + j];
#pragma unroll
    for (int qr = 0; qr < 8; ++qr)
#pragma unroll
      for (int qc = 0; qc < 8; ++qc) acc[qr][qc] = fmaf(a[qr], d[qc], acc[qr][qc]);
  }
#pragma unroll
  for (int qr = 0; qr < 8; ++qr)
#pragma unroll
    for (int qc = 0; qc < 8; ++qc) {
      size_t o = (size_t)(rs1 + ty * 8 + qr) * kN + rs2 + tx * 8 + qc;
      Ab[o] -= acc[qr][qc];
    }
}

// ---------------- G_ik = L_ik * D_k ----------------
__global__ __launch_bounds__(256) void build_G(const float* __restrict__ A,
                                               const float* __restrict__ Dg,
                                               float* __restrict__ G) {
  __shared__ float Lt[128 * 129];
  __shared__ float Dt[128 * 129];
  int b = blockIdx.y;
  int pid = blockIdx.x;
  int i = 1;
  while ((i * (i + 1)) / 2 <= pid) ++i;
  int k = pid - (i * (i - 1)) / 2;
  const float* Ab = A + (size_t)b * kN * kN;
  const float* Db = Dg + (size_t)(b * 8 + k) * 16384;
  int t = threadIdx.x;
  for (int q = 0; q < 64; ++q) {
    int li = t + 256 * q;
    int r = li >> 7, cc = li & 127;
    Lt[r * 129 + cc] = Ab[(size_t)(i * 128 + r) * kN + k * 128 + cc];
    Dt[r * 129 + cc] = Db[r * 128 + cc];
  }
  __syncthreads();
  int tx = t & 15, ty = t >> 4;
  float acc[8][8] = {};
  for (int j = 0; j < 128; ++j) {
    float a[8], d[8];
#pragma unroll
    for (int q = 0; q < 8; ++q) a[q] = Lt[(ty * 8 + q) * 129 + j];
#pragma unroll
    for (int q = 0; q < 8; ++q) d[q] = Dt[j * 129 + tx * 8 + q];
#pragma unroll
    for (int qr = 0; qr < 8; ++qr)
#pragma unroll
      for (int qc = 0; qc < 8; ++qc) acc[qr][qc] = fmaf(a[qr], d[qc], acc[qr][qc]);
  }
  float* Gb = G + (size_t)(b * 28 + pid) * 16384;
#pragma unroll
  for (int qr = 0; qr < 8; ++qr)
#pragma unroll
    for (int qc = 0; qc < 8; ++qc)
      Gb[(ty * 8 + qr) * 128 + tx * 8 + qc] = acc[qr][qc];
}

// ---------------- z = L^-1 (y - mean), nlml ----------------
__global__ __launch_bounds__(128) void solve_small(
    const float* __restrict__ A, const float* __restrict__ Dg,
    const float* __restrict__ y, const float* __restrict__ meanp,
    float* __restrict__ zbuf, float* __restrict__ out) {
  __shared__ __align__(16) float zs[1024];
  __shared__ float ts[128];
  __shared__ float red[128];
  int b = blockIdx.x, t = threadIdx.x;
  const float* Ab = A + (size_t)b * kN * kN;
  float mv = meanp[b];
  for (int q = t; q < 1024; q += 128) zs[q] = y[b * kN + q] - mv;
  __syncthreads();
  for (int i = 0; i < 8; ++i) {
    float acc = zs[i * 128 + t];
    const float* Lrow = Ab + (size_t)(i * 128 + t) * kN;
    for (int kk = 0; kk < i * 128; kk += 4) {
      float4 lv = *(const float4*)&Lrow[kk];
      float4 zv = *(const float4*)&zs[kk];
      acc -= lv.x * zv.x + lv.y * zv.y + lv.z * zv.z + lv.w * zv.w;
    }
    ts[t] = acc;
    __syncthreads();
    const float* Db = Dg + (size_t)(b * 8 + i) * 16384 + t * 128;
    float zv = 0.0f;
    for (int c = 0; c <= t; ++c) zv += Db[c] * ts[c];
    zs[i * 128 + t] = zv;
    __syncthreads();
  }
  float df = 0.0f, ld = 0.0f;
  for (int q = t; q < 1024; q += 128) {
    df += zs[q] * zs[q];
    ld += logf(Ab[(size_t)q * kN + q]);
  }
  red[t] = df;
  __syncthreads();
  for (int s = 64; s > 0; s >>= 1) {
    if (t < s) red[t] += red[t + s];
    __syncthreads();
  }
  float dfs = red[0];
  __syncthreads();
  red[t] = ld;
  __syncthreads();
  for (int s = 64; s > 0; s >>= 1) {
    if (t < s) red[t] += red[t + s];
    __syncthreads();
  }
  if (t == 0)
    out[2 * kB * kM + b] = 0.5f * dfs + red[0] + 0.5f * 1024.0f * logf(6.283185307179586f);
  for (int q = t; q < 1024; q += 128) zbuf[b * kN + q] = zs[q];
}

// ---------------- K_nm ----------------
__global__ __launch_bounds__(256) void build_Knm(
    const float* __restrict__ xt, const float* __restrict__ pt,
    const float* __restrict__ xs, const float* __restrict__ ps,
    const float* __restrict__ sp, float* __restrict__ Kw) {
  size_t idx = (size_t)blockIdx.x * 256 + threadIdx.x;  // B*N*M
  int b = (int)(idx / ((size_t)kN * kM));
  int n = (int)((idx / kM) % kN);
  int m = (int)(idx % kM);
  float scale = __expf(sp[0]);
  const float* x1 = xt + ((size_t)b * kN + n) * 2;
  const float* p1 = pt + ((size_t)b * kN + n) * 3;
  const float* x2 = xs + ((size_t)b * kM + m) * 2;
  const float* p2 = ps + ((size_t)b * kM + m) * 3;
  Kw[idx] = pair_kernel(x1[0], x1[1], p1[0], p1[1], p1[2],
                        x2[0], x2[1], p2[0], p2[1], p2[2], scale);
}

// ---------------- S_i = K_i - sum_{k<i} G_ik S_k (in place) ----------------
__global__ __launch_bounds__(256) void trsm_step(const float* __restrict__ G,
                                                 float* __restrict__ Kw, int ib) {
  __shared__ float At[32 * 132];
  __shared__ float Bt[32 * 132];
  int b = blockIdx.y;
  int m0 = blockIdx.x * 128;
  int t = threadIdx.x;
  int tx = t & 15, ty = t >> 4;
  float acc[8][8] = {};
  for (int kb = 0; kb < ib; ++kb) {
    const float* Gblk = G + (size_t)(b * 28 + (ib * (ib - 1)) / 2 + kb) * 16384;
    for (int kc = 0; kc < 128; kc += 32) {
#pragma unroll
      for (int q = 0; q < 4; ++q) {
        int li = t + 256 * q;
        int r = li >> 3, k4 = li & 7;
        float4 v = *(const float4*)(Gblk + r * 128 + kc + k4 * 4);
        At[(k4 * 4 + 0) * 132 + r] = v.x;
        At[(k4 * 4 + 1) * 132 + r] = v.y;
        At[(k4 * 4 + 2) * 132 + r] = v.z;
        At[(k4 * 4 + 3) * 132 + r] = v.w;
      }
#pragma unroll
      for (int q = 0; q < 4; ++q) {
        int li = t + 256 * q;
        int kk = li >> 5, m4 = li & 31;
        float4 v = *(const float4*)(Kw + ((size_t)b * kN + kb * 128 + kc + kk) * kM + m0 + m4 * 4);
        *(float4*)(Bt + kk * 132 + m4 * 4) = v;
      }
      __syncthreads();
#pragma unroll
      for (int kk = 0; kk < 32; ++kk) {
        float a[8], w[8];
        *(float4*)a = *(const float4*)(At + kk * 132 + ty * 8);
        *(float4*)(a + 4) = *(const float4*)(At + kk * 132 + ty * 8 + 4);
        *(float4*)w = *(const float4*)(Bt + kk * 132 + tx * 8);
        *(float4*)(w + 4) = *(const float4*)(Bt + kk * 132 + tx * 8 + 4);
#pragma unroll
        for (int qr = 0; qr < 8; ++qr)
#pragma unroll
          for (int qc = 0; qc < 8; ++qc) acc[qr][qc] = fmaf(a[qr], w[qc], acc[qr][qc]);
      }
      __syncthreads();
    }
  }
#pragma unroll
  for (int qr = 0; qr < 8; ++qr) {
    float* rowp = Kw + ((size_t)b * kN + ib * 128 + ty * 8 + qr) * kM + m0 + tx * 8;
    float4 k0 = *(const float4*)rowp;
    float4 k1 = *(const float4*)(rowp + 4);
    k0.x -= acc[qr][0]; k0.y -= acc[qr][1]; k0.z -= acc[qr][2]; k0.w -= acc[qr][3];
    k1.x -= acc[qr][4]; k1.y -= acc[qr][5]; k1.z -= acc[qr][6]; k1.w -= acc[qr][7];
    *(float4*)rowp = k0;
    *(float4*)(rowp + 4) = k1;
  }
}

// ---------------- w_i = D_i S_i (in place, all blocks) ----------------
__global__ __launch_bounds__(256) void dmult(const float* __restrict__ Dg,
                                             float* __restrict__ Kw) {
  __shared__ float At[32 * 132];
  __shared__ float Bt[32 * 132];
  int b = blockIdx.y >> 3;
  int ib = blockIdx.y & 7;
  int m0 = blockIdx.x * 128;
  const float* Db = Dg + (size_t)(b * 8 + ib) * 16384;
  int t = threadIdx.x;
  int tx = t & 15, ty = t >> 4;
  float acc[8][8] = {};
  for (int kc = 0; kc < 128; kc += 32) {
#pragma unroll
    for (int q = 0; q < 4; ++q) {
      int li = t + 256 * q;
      int r = li >> 3, c4 = li & 7;
      float4 v = *(const float4*)(Db + r * 128 + kc + c4 * 4);
      At[(c4 * 4 + 0) * 132 + r] = v.x;
      At[(c4 * 4 + 1) * 132 + r] = v.y;
      At[(c4 * 4 + 2) * 132 + r] = v.z;
      At[(c4 * 4 + 3) * 132 + r] = v.w;
    }
#pragma unroll
    for (int q = 0; q < 4; ++q) {
      int li = t + 256 * q;
      int kk = li >> 5, m4 = li & 31;
      float4 v = *(const float4*)(Kw + ((size_t)b * kN + ib * 128 + kc + kk) * kM + m0 + m4 * 4);
      *(float4*)(Bt + kk * 132 + m4 * 4) = v;
    }
    __syncthreads();
#pragma unroll
    for (int kk = 0; kk < 32; ++kk) {
      float a[8], w[8];
      *(float4*)a = *(const float4*)(At + kk * 132 + ty * 8);
      *(float4*)(a + 4) = *(const float4*)(At + kk * 132 + ty * 8 + 4);
      *(float4*)w = *(const float4*)(Bt + kk * 132 + tx * 8);
      *(float4*)(w + 4) = *(const float4*)(Bt + kk * 132 + tx * 8 + 4);
#pragma unroll
      for (int qr = 0; qr < 8; ++qr)
#pragma unroll
        for (int qc = 0; qc < 8; ++qc) acc[qr][qc] = fmaf(a[qr], w[qc], acc[qr][qc]);
    }
    __syncthreads();
  }
#pragma unroll
  for (int qr = 0; qr < 8; ++qr) {
    float* dst = Kw + ((size_t)b * kN + ib * 128 + ty * 8 + qr) * kM + m0 + tx * 8;
    float4 v0 = {acc[qr][0], acc[qr][1], acc[qr][2], acc[qr][3]};
    float4 v1 = {acc[qr][4], acc[qr][5], acc[qr][6], acc[qr][7]};
    *(float4*)dst = v0;
    *(float4*)(dst + 4) = v1;
  }
}

// ---------------- pred_mean / pred_var ----------------
__global__ __launch_bounds__(256) void finalize(
    const float* __restrict__ Kw, const float* __restrict__ zbuf,
    const float* __restrict__ ps, const float* __restrict__ sp,
    const float* __restrict__ meanp, float* __restrict__ out) {
  int idx = blockIdx.x * 256 + threadIdx.x;  // B*M
  int b = idx / kM;
  int m = idx % kM;
  __shared__ float zsh[1024];
  for (int q = threadIdx.x; q < 1024; q += 256) zsh[q] = zbuf[b * kN + q];
  __syncthreads();
  float pm = 0.0f, s2 = 0.0f;
  const float* col = Kw + (size_t)b * kN * kM + m;
  for (int n = 0; n < kN; ++n) {
    float wv = col[(size_t)n * kM];
    pm = fmaf(wv, zsh[n], pm);
    s2 = fmaf(wv, wv, s2);
  }
  float a = ps[(size_t)(b * kM + m) * 3 + 0];
  float bb = ps[(size_t)(b * kM + m) * 3 + 1];
  float c = ps[(size_t)(b * kM + m) * 3 + 2];
  float det = a * bb - c * c;
  float C = 2.0f * sqrtf(det) * rsqrtf(fmaxf(4.0f * det, 1e-5f));
  float t0 = kSqrt3 * sqrtf(1e-5f);
  float mat = (1.0f + t0) * __expf(-t0);
  float scale = __expf(sp[0]);
  float kd = C * mat * scale;
  out[b * kM + m] = meanp[b] + pm;
  out[kB * kM + b * kM + m] = kd - s2;
}

extern "C" void kernel_launch(void* const* d_in, const int* in_sizes, int n_in,
                              void* d_out, int out_size, void* d_ws, size_t ws_size,
                              hipStream_t stream) {
  const float* xt = (const float*)d_in[0];   // coords_train [B,N,2]
  const float* pt = (const float*)d_in[1];   // kernel_params_train [B,N,3]
  const float* xs = (const float*)d_in[2];   // coords_test [B,M,2]
  const float* ps = (const float*)d_in[3];   // kernel_params_test [B,M,3]
  const float* y = (const float*)d_in[4];    // y_train [B,N,1]
  const float* var = (const float*)d_in[5];  // var [B,N]
  const float* meanp = (const float*)d_in[6];// mean [B,1,1]
  const float* sp = (const float*)d_in[7];   // scale_param [1]
  float* out = (float*)d_out;
  float* ws = (float*)d_ws;
  if (ws_size < WS_FLOATS * sizeof(float)) return;  // workspace too small -> fail loudly

  float* A = ws + A_OFF;
  float* Dg = ws + D_OFF;
  float* G = ws + G_OFF;
  float* zbuf = ws + Z_OFF;
  float* Kw = ws + K_OFF;

  build_A<<<(kB * kN * kN) / 256, 256, 0, stream>>>(xt, pt, var, sp, A);
  for (int p = 0; p < 8; ++p) {
    chol_panel<<<kB, 1024, 0, stream>>>(A, Dg, p);
    if (p < 7) {
      int nt = 7 - p;
      chol_trsm<<<dim3(nt, kB), 256, 0, stream>>>(A, Dg, p);
      chol_syrk<<<dim3(nt * (nt + 1) / 2, kB), 256, 0, stream>>>(A, p);
    }
  }
  build_G<<<dim3(28, kB), 256, 0, stream>>>(A, Dg, G);
  solve_small<<<kB, 128, 0, stream>>>(A, Dg, y, meanp, zbuf, out);
  build_Knm<<<(int)(((size_t)kB * kN * kM) / 256), 256, 0, stream>>>(xt, pt, xs, ps, sp, Kw);
  for (int i = 1; i < 8; ++i)
    trsm_step<<<dim3(kM / 128, kB), 256, 0, stream>>>(G, Kw, i);
  dmult<<<dim3(kM / 128, kB * 8), 256, 0, stream>>>(Dg, Kw);
  finalize<<<(kB * kM) / 256, 256, 0, stream>>>(Kw, zbuf, ps, sp, meanp, out);
}